// Round 7
// baseline (189.811 us; speedup 1.0000x reference)
//
#include <hip/hip_runtime.h>
#include <hip/hip_fp16.h>
#include <math.h>

#define NB   16     // batch
#define IMG  128    // input image side
#define NANG 300
#define NDET 300
#define WB   148    // canvas live box: x,y in [76,224)

typedef _Float16 v2h __attribute__((ext_vector_type(2)));

// Gaussian taps: sigma_img -> 2^(-d^2/2); sigma_att -> 2^(-d^2/8). f64 normalize, f32 cast.
__device__ __constant__ float KE[9] = {
  (float)(0.00390625            / 3.0104144100214136),
  (float)(0.04419417382415922   / 3.0104144100214136),
  (float)(0.25                  / 3.0104144100214136),
  (float)(0.7071067811865476    / 3.0104144100214136),
  (float)(1.0                   / 3.0104144100214136),
  (float)(0.7071067811865476    / 3.0104144100214136),
  (float)(0.25                  / 3.0104144100214136),
  (float)(0.04419417382415922   / 3.0104144100214136),
  (float)(0.00390625            / 3.0104144100214136)
};
__device__ __constant__ float KA[17] = {
  (float)(0.00390625            / 6.019333926786741),
  (float)(0.014328188175072987  / 6.019333926786741),
  (float)(0.04419417382415922   / 6.019333926786741),
  (float)(0.11462550540058389   / 6.019333926786741),
  (float)(0.25                  / 6.019333926786741),
  (float)(0.4585020216023356    / 6.019333926786741),
  (float)(0.7071067811865476    / 6.019333926786741),
  (float)(0.9170040432046712    / 6.019333926786741),
  (float)(1.0                   / 6.019333926786741),
  (float)(0.9170040432046712    / 6.019333926786741),
  (float)(0.7071067811865476    / 6.019333926786741),
  (float)(0.4585020216023356    / 6.019333926786741),
  (float)(0.25                  / 6.019333926786741),
  (float)(0.11462550540058389   / 6.019333926786741),
  (float)(0.04419417382415922   / 6.019333926786741),
  (float)(0.014328188175072987  / 6.019333926786741),
  (float)(0.00390625            / 6.019333926786741)
};

__device__ __forceinline__ unsigned h16(float f) {
  return (unsigned)__half_as_ushort(__float2half_rn(f));
}
__device__ __forceinline__ v2h pk16(float a, float b) {
  return __builtin_bit_cast(v2h, __builtin_amdgcn_cvt_pkrtz(a, b));
}

// K1: fused pad+blur -> f16 pair canvas over the live box [76,224)^2.
// Q[y'][x'][b] = uint2{ E(y,x)|E(y,x+1)<<16 , A'(y,x)|A'(y,x+1)<<16 }  (f16, A'=0.01*A)
// One 16x16 canvas tile per block per batch; separable 2-D blur recomputed per tile in LDS.
// E(y,x) = sum_{dy,dx<9} KE.KE.img[y-90+dy][x-90+dx] ; A: 17 taps, offset -94.
__global__ void k_prep(const float* __restrict__ img, const float* __restrict__ att,
                       uint2* __restrict__ Q) {
  __shared__ float sImg[24 * 25];   // rows 24, cols 25 (tile 16 + halo 8 + pair col)
  __shared__ float sAtt[32 * 33];   // rows 32, cols 33
  __shared__ float sEi[24 * 17];    // h-blurred E, cols 0..16
  __shared__ float sAi[32 * 17];

  int tid = threadIdx.x;
  int tx = tid & 15, ty = tid >> 4;
  int X0 = blockIdx.x * 16;         // canvas-box coords
  int Y0 = blockIdx.y * 16;
  int b  = blockIdx.z;
  // img row for sImg r: (Y0+76)-90+r = Y0-14+r ; col: X0-14+c
  const float* imb = img + b * IMG * IMG;
  const float* atb = att + b * IMG * IMG;
  for (int t = tid; t < 24 * 25; t += 256) {
    int r = t / 25, c = t % 25;
    int ir = Y0 - 14 + r, ic = X0 - 14 + c;
    bool v = (ir >= 0) & (ir < IMG) & (ic >= 0) & (ic < IMG);
    sImg[t] = v ? imb[ir * IMG + ic] : 0.f;
  }
  // att row for sAtt r: Y0-18+r ; col X0-18+c
  for (int t = tid; t < 32 * 33; t += 256) {
    int r = t / 33, c = t % 33;
    int ir = Y0 - 18 + r, ic = X0 - 18 + c;
    bool v = (ir >= 0) & (ir < IMG) & (ic >= 0) & (ic < IMG);
    sAtt[t] = v ? atb[ir * IMG + ic] : 0.f;
  }
  __syncthreads();
  for (int t = tid; t < 24 * 17; t += 256) {
    int r = t / 17, c = t % 17;
    float acc = 0.f;
#pragma unroll
    for (int d = 0; d < 9; ++d) acc = fmaf(KE[d], sImg[r * 25 + c + d], acc);
    sEi[t] = acc;
  }
  for (int t = tid; t < 32 * 17; t += 256) {
    int r = t / 17, c = t % 17;
    float acc = 0.f;
#pragma unroll
    for (int d = 0; d < 17; ++d) acc = fmaf(KA[d], sAtt[r * 33 + c + d], acc);
    sAi[t] = acc;
  }
  __syncthreads();
  int xc = X0 + tx, yc = Y0 + ty;
  if (xc >= WB || yc >= WB) return;
  float E0 = 0.f, E1 = 0.f, A0 = 0.f, A1 = 0.f;
#pragma unroll
  for (int d = 0; d < 9; ++d) {
    float k = KE[d];
    E0 = fmaf(k, sEi[(ty + d) * 17 + tx], E0);
    E1 = fmaf(k, sEi[(ty + d) * 17 + tx + 1], E1);
  }
#pragma unroll
  for (int d = 0; d < 17; ++d) {
    float k = KA[d];
    A0 = fmaf(k, sAi[(ty + d) * 17 + tx], A0);
    A1 = fmaf(k, sAi[(ty + d) * 17 + tx + 1], A1);
  }
  uint2 q;
  q.x = h16(E0) | (h16(E1) << 16);
  q.y = h16(0.01f * A0) | (h16(0.01f * A1) << 16);
  Q[(yc * WB + xc) * NB + b] = q;
}

// K2: radon for E and A together. Lanes: b = tid&15 (16 lanes read 128 B contiguous
// per row-load), 4 bins/wave, TWO dwordx2 per sample (rows y0, y0+1; second via
// uniform base Pc2 -> no extra VALU). 8x unrolled, 16 loads in flight.
// Tail samples clamped to chord end 'hi' -> guaranteed-zero canvas -> exact 0.
__global__ void k_radon(const uint2* __restrict__ Qp, float* __restrict__ S) {
  int t = threadIdx.x;
  int b  = t & 15;
  int jj = t >> 4;
  int j  = blockIdx.x * 16 + jj;
  int a  = blockIdx.y;
  if (j >= NDET) return;
  float th = (float)a * (float)(3.14159265358979323846 / 299.0);
  float c = cosf(th), s = sinf(th);
  float xj = fmaf((float)j, (float)(2.0 / 299.0), -1.0f);
  // px(i) = pb + s*i ; py(i) = qb + c*i (unit step)
  float pb = fmaf(c,  xj, 1.0f) * 149.5f - 149.5f * s;
  float qb = fmaf(-s, xj, 1.0f) * 149.5f - 149.5f * c;
  const float L = 76.5f, H = 222.5f;
  float lo = 0.f, hi = 299.0f;
  if (s > 1e-6f) {                       // s >= 0 for theta in [0,180]
    float inv = 1.0f / s;
    lo = fmaxf(lo, (L - pb) * inv); hi = fminf(hi, (H - pb) * inv);
  } else if (pb < L || pb > H) { hi = -1.f; }
  if (fabsf(c) > 1e-6f) {
    float inv = 1.0f / c;
    float t0 = (L - qb) * inv, t1 = (H - qb) * inv;
    lo = fmaxf(lo, fminf(t0, t1)); hi = fminf(hi, fmaxf(t0, t1));
  } else if (qb < L || qb > H) { hi = -1.f; }
  int i0 = (int)ceilf(lo);
  int i1 = (int)floorf(hi);

  float sE0 = 0.f, sE1 = 0.f, sA0 = 0.f, sA1 = 0.f;
  // byte offset for (y0,x0): ((y0-76)*148 + (x0-76))*128 + b*8
  const char* Pc  = (const char*)Qp;
  const char* Pc2 = Pc + WB * NB * 8;    // next canvas row, uniform
  int boff = b * 8 - 76 * (WB + 1) * NB * 8;

  float fbase = (float)i0;
  for (int i = i0; i <= i1; i += 8, fbase += 8.0f) {
    uint2 q0[8], q1[8];
    float wyv[8];
    v2h oxp[8];
#pragma unroll
    for (int u = 0; u < 8; ++u) {
      float fi = fminf(fbase + (float)u, hi);   // tail -> chord end -> zero canvas
      float px = fmaf(fi, s, pb);
      float py = fmaf(fi, c, qb);
      float x0f = floorf(px), y0f = floorf(py);
      float wx = px - x0f;
      wyv[u] = py - y0f;
      int idx = (int)fmaf(y0f, (float)WB, x0f);
      int off = (idx << 7) + boff;
      q0[u] = *(const uint2*)(Pc  + off);
      q1[u] = *(const uint2*)(Pc2 + off);
      oxp[u] = pk16(1.0f - wx, wx);
    }
#pragma unroll
    for (int u = 0; u < 8; ++u) {
      float wy = wyv[u], omy = 1.0f - wy;
      float de0 = __builtin_amdgcn_fdot2(__builtin_bit_cast(v2h, q0[u].x), oxp[u], 0.0f, false);
      float da0 = __builtin_amdgcn_fdot2(__builtin_bit_cast(v2h, q0[u].y), oxp[u], 0.0f, false);
      float de1 = __builtin_amdgcn_fdot2(__builtin_bit_cast(v2h, q1[u].x), oxp[u], 0.0f, false);
      float da1 = __builtin_amdgcn_fdot2(__builtin_bit_cast(v2h, q1[u].y), oxp[u], 0.0f, false);
      if (u & 1) { sE1 = fmaf(omy, de0, fmaf(wy, de1, sE1)); sA1 = fmaf(omy, da0, fmaf(wy, da1, sA1)); }
      else       { sE0 = fmaf(omy, de0, fmaf(wy, de1, sE0)); sA0 = fmaf(omy, da0, fmaf(wy, da1, sA0)); }
    }
  }
  float sumE = sE0 + sE1, sumA = sA0 + sA1;
  S[(a * NB + b) * NDET + j] = sumE * expf(-2.0f * sumA);  // VOXEL_MM = 2; layout [a][b][j]
}

// K3: per-angle 5-tap detector blur (reflect) + scale. S is [a][b][j] -> fully
// coalesced reads along j; out [b][a][j] coalesced writes.
__global__ void k_dblur(const float* __restrict__ S, const float* __restrict__ scale,
                        float* __restrict__ out) {
  int j = threadIdx.x;
  int a = blockIdx.x;
  int b = blockIdx.y;
  if (j >= NDET) return;
  float th = (float)a * (float)(3.14159265358979323846 / 299.0);
  float c = cosf(th), s = sinf(th);
  float u = fabsf(c) + fabsf(s);          // bw = 2u
  float u2 = u * u;
  float e1 = exp2f(-2.0f * u2);
  float e2 = exp2f(-8.0f * u2);
  float norm = 1.0f / (1.0f + 2.0f * (e1 + e2));
  float w2c = norm, w1c = e1 * norm, w0c = e2 * norm;
  const float* row = S + (a * NB + b) * NDET;
  float acc = 0.f;
#pragma unroll
  for (int tt = -2; tt <= 2; ++tt) {
    int jr = j + tt;
    if (jr < 0) jr = -jr;
    if (jr > 299) jr = 598 - jr;
    float w = (tt == 0) ? w2c : ((tt == 1 || tt == -1) ? w1c : w0c);
    acc = fmaf(w, row[jr], acc);
  }
  out[(b * NANG + a) * NDET + j] = acc * scale[b];
}

extern "C" void kernel_launch(void* const* d_in, const int* in_sizes, int n_in,
                              void* d_out, int out_size, void* d_ws, size_t ws_size,
                              hipStream_t stream) {
  const float* img   = (const float*)d_in[0];
  const float* att   = (const float*)d_in[1];
  const float* scale = (const float*)d_in[2];
  float* out = (float*)d_out;
  float* ws  = (float*)d_ws;

  // ws layout (floats): Q 148*148*16 uint2 (2.80 MB) | S 300*300*16 (5.76 MB)
  uint2*  Q  = (uint2*)ws;
  float*  S  = ws + 700928;

  k_prep <<<dim3(10, 10, NB), 256, 0, stream>>>(img, att, Q);
  k_radon<<<dim3(19, NANG),   256, 0, stream>>>(Q, S);
  k_dblur<<<dim3(NANG, NB),   320, 0, stream>>>(S, scale, out);
}

// Round 8
// 163.687 us; speedup vs baseline: 1.1596x; 1.1596x over previous
//
#include <hip/hip_runtime.h>
#include <hip/hip_fp16.h>
#include <math.h>

#define NB   16     // batch
#define IMG  128    // input image side
#define NANG 300
#define NDET 300
#define WB   148    // canvas live box: x,y in [76,224)

typedef _Float16 v2h __attribute__((ext_vector_type(2)));

// Gaussian taps: sigma_img -> 2^(-d^2/2); sigma_att -> 2^(-d^2/8). f64 normalize, f32 cast.
__device__ __constant__ float KE[9] = {
  (float)(0.00390625            / 3.0104144100214136),
  (float)(0.04419417382415922   / 3.0104144100214136),
  (float)(0.25                  / 3.0104144100214136),
  (float)(0.7071067811865476    / 3.0104144100214136),
  (float)(1.0                   / 3.0104144100214136),
  (float)(0.7071067811865476    / 3.0104144100214136),
  (float)(0.25                  / 3.0104144100214136),
  (float)(0.04419417382415922   / 3.0104144100214136),
  (float)(0.00390625            / 3.0104144100214136)
};
__device__ __constant__ float KA[17] = {
  (float)(0.00390625            / 6.019333926786741),
  (float)(0.014328188175072987  / 6.019333926786741),
  (float)(0.04419417382415922   / 6.019333926786741),
  (float)(0.11462550540058389   / 6.019333926786741),
  (float)(0.25                  / 6.019333926786741),
  (float)(0.4585020216023356    / 6.019333926786741),
  (float)(0.7071067811865476    / 6.019333926786741),
  (float)(0.9170040432046712    / 6.019333926786741),
  (float)(1.0                   / 6.019333926786741),
  (float)(0.9170040432046712    / 6.019333926786741),
  (float)(0.7071067811865476    / 6.019333926786741),
  (float)(0.4585020216023356    / 6.019333926786741),
  (float)(0.25                  / 6.019333926786741),
  (float)(0.11462550540058389   / 6.019333926786741),
  (float)(0.04419417382415922   / 6.019333926786741),
  (float)(0.014328188175072987  / 6.019333926786741),
  (float)(0.00390625            / 6.019333926786741)
};

__device__ __forceinline__ unsigned h16(float f) {
  return (unsigned)__half_as_ushort(__float2half_rn(f));
}
__device__ __forceinline__ v2h pk16(float a, float b) {
  return __builtin_bit_cast(v2h, __builtin_amdgcn_cvt_pkrtz(a, b));
}

// K1: fused pad+blur -> f16 quad canvas over the live box [76,224)^2.
// Q[y'][x'][b] = uint4{ E00|E01<<16, E10|E11<<16, A00|A01<<16, A10|A11<<16 }
// (f16 pairs; suffix (r,c) = (y+r, x+c); A pre-scaled 0.01). Whole 2x2 bilinear
// footprint of both images in ONE 16-B load for k_radon.
// E(y,x) = sum KE[dy]KE[dx] img[y+76-90+dy][x+76-90+dx]; A: 17 taps, offset -94.
__global__ void k_prep(const float* __restrict__ img, const float* __restrict__ att,
                       uint4* __restrict__ Q) {
  __shared__ float sImg[25 * 25];   // img rows Y0-14 .. Y0+10, cols X0-14 .. X0+10
  __shared__ float sAtt[33 * 33];   // att rows Y0-18 .. Y0+14, cols X0-18 .. X0+14
  __shared__ float sEi[25 * 17];    // h-blurred E rows, canvas cols X0 .. X0+16
  __shared__ float sAi[33 * 17];

  int tid = threadIdx.x;
  int tx = tid & 15, ty = tid >> 4;
  int X0 = blockIdx.x * 16;         // canvas-box coords
  int Y0 = blockIdx.y * 16;
  int b  = blockIdx.z;
  const float* imb = img + b * IMG * IMG;
  const float* atb = att + b * IMG * IMG;
  for (int t = tid; t < 625; t += 256) {
    int r = t / 25, c = t - r * 25;
    int ir = Y0 - 14 + r, ic = X0 - 14 + c;
    bool v = (ir >= 0) & (ir < IMG) & (ic >= 0) & (ic < IMG);
    sImg[t] = v ? imb[ir * IMG + ic] : 0.f;
  }
  for (int t = tid; t < 1089; t += 256) {
    int r = t / 33, c = t - r * 33;
    int ir = Y0 - 18 + r, ic = X0 - 18 + c;
    bool v = (ir >= 0) & (ir < IMG) & (ic >= 0) & (ic < IMG);
    sAtt[t] = v ? atb[ir * IMG + ic] : 0.f;
  }
  __syncthreads();
  for (int t = tid; t < 425; t += 256) {   // 25*17
    int r = t / 17, c = t - r * 17;
    float acc = 0.f;
#pragma unroll
    for (int d = 0; d < 9; ++d) acc = fmaf(KE[d], sImg[r * 25 + c + d], acc);
    sEi[t] = acc;
  }
  for (int t = tid; t < 561; t += 256) {   // 33*17
    int r = t / 17, c = t - r * 17;
    float acc = 0.f;
#pragma unroll
    for (int d = 0; d < 17; ++d) acc = fmaf(KA[d], sAtt[r * 33 + c + d], acc);
    sAi[t] = acc;
  }
  __syncthreads();
  int xc = X0 + tx, yc = Y0 + ty;
  if (xc >= WB || yc >= WB) return;
  float E00 = 0.f, E01 = 0.f, E10 = 0.f, E11 = 0.f;
  float A00 = 0.f, A01 = 0.f, A10 = 0.f, A11 = 0.f;
#pragma unroll
  for (int d = 0; d < 9; ++d) {
    float k = KE[d];
    E00 = fmaf(k, sEi[(ty + d) * 17 + tx],     E00);
    E01 = fmaf(k, sEi[(ty + d) * 17 + tx + 1], E01);
    E10 = fmaf(k, sEi[(ty + 1 + d) * 17 + tx],     E10);
    E11 = fmaf(k, sEi[(ty + 1 + d) * 17 + tx + 1], E11);
  }
#pragma unroll
  for (int d = 0; d < 17; ++d) {
    float k = KA[d];
    A00 = fmaf(k, sAi[(ty + d) * 17 + tx],     A00);
    A01 = fmaf(k, sAi[(ty + d) * 17 + tx + 1], A01);
    A10 = fmaf(k, sAi[(ty + 1 + d) * 17 + tx],     A10);
    A11 = fmaf(k, sAi[(ty + 1 + d) * 17 + tx + 1], A11);
  }
  uint4 q;
  q.x = h16(E00) | (h16(E01) << 16);
  q.y = h16(E10) | (h16(E11) << 16);
  q.z = h16(0.01f * A00) | (h16(0.01f * A01) << 16);
  q.w = h16(0.01f * A10) | (h16(0.01f * A11) << 16);
  Q[(yc * WB + xc) * NB + b] = q;
}

// K2: radon for E and A together. Lanes: b = tid&15 (coalesced 256-B pixel lines),
// 4 bins/wave, ONE dwordx4 per sample, bilinear via 4x v_dot2_f32_f16.
// launch_bounds(256,2): relax VGPR cap so the 8 unrolled loads stay in flight.
// Tail samples clamped to chord end 'hi' -> guaranteed-zero canvas -> exact 0.
__global__ void __launch_bounds__(256, 2)
k_radon(const uint4* __restrict__ P, float* __restrict__ S) {
  int t = threadIdx.x;
  int b  = t & 15;
  int jj = t >> 4;
  int j  = blockIdx.x * 16 + jj;
  int a  = blockIdx.y;
  if (j >= NDET) return;
  float th = (float)a * (float)(3.14159265358979323846 / 299.0);
  float c = cosf(th), s = sinf(th);
  float xj = fmaf((float)j, (float)(2.0 / 299.0), -1.0f);
  // px(i) = pb + s*i ; py(i) = qb + c*i (unit step)
  float pb = fmaf(c,  xj, 1.0f) * 149.5f - 149.5f * s;
  float qb = fmaf(-s, xj, 1.0f) * 149.5f - 149.5f * c;
  const float L = 76.5f, H = 222.5f;
  float lo = 0.f, hi = 299.0f;
  if (s > 1e-6f) {                       // s >= 0 for theta in [0,180]
    float inv = 1.0f / s;
    lo = fmaxf(lo, (L - pb) * inv); hi = fminf(hi, (H - pb) * inv);
  } else if (pb < L || pb > H) { hi = -1.f; }
  if (fabsf(c) > 1e-6f) {
    float inv = 1.0f / c;
    float t0 = (L - qb) * inv, t1 = (H - qb) * inv;
    lo = fmaxf(lo, fminf(t0, t1)); hi = fminf(hi, fmaxf(t0, t1));
  } else if (qb < L || qb > H) { hi = -1.f; }
  int i0 = (int)ceilf(lo);
  int i1 = (int)floorf(hi);

  float sE0 = 0.f, sE1 = 0.f, sA0 = 0.f, sA1 = 0.f;
  // byte offset: ((y0-76)*148 + (x0-76))*256 + b*16
  const char* Pc = (const char*)P;
  int boff = b * 16 - 76 * 149 * 256;

  for (int i = i0; i <= i1; i += 8) {
    uint4 q[8];
    v2h w0[8], w1[8];
#pragma unroll
    for (int u = 0; u < 8; ++u) {
      float fi = fminf((float)(i + u), hi);   // tail -> chord end -> zero canvas
      float px = fmaf(fi, s, pb);
      float py = fmaf(fi, c, qb);
      float x0f = floorf(px), y0f = floorf(py);
      float wx = px - x0f, wy = py - y0f;
      int idx = (int)fmaf(y0f, (float)WB, x0f);
      int off = idx * 256 + boff;
      q[u] = *(const uint4*)(Pc + off);
      float omx = 1.0f - wx, omy = 1.0f - wy;
      w0[u] = pk16(omy * omx, omy * wx);  // (w00, w01)
      w1[u] = pk16(wy * omx,  wy * wx);   // (w10, w11)
    }
#pragma unroll
    for (int u = 0; u < 8; ++u) {
      v2h e0 = __builtin_bit_cast(v2h, q[u].x);
      v2h e1 = __builtin_bit_cast(v2h, q[u].y);
      v2h a0 = __builtin_bit_cast(v2h, q[u].z);
      v2h a1 = __builtin_bit_cast(v2h, q[u].w);
      sE0 = __builtin_amdgcn_fdot2(e0, w0[u], sE0, false);
      sE1 = __builtin_amdgcn_fdot2(e1, w1[u], sE1, false);
      sA0 = __builtin_amdgcn_fdot2(a0, w0[u], sA0, false);
      sA1 = __builtin_amdgcn_fdot2(a1, w1[u], sA1, false);
    }
  }
  float sumE = sE0 + sE1, sumA = sA0 + sA1;
  S[(a * NB + b) * NDET + j] = sumE * expf(-2.0f * sumA);  // VOXEL_MM = 2; layout [a][b][j]
}

// K3: per-angle 5-tap detector blur (reflect) + scale. S is [a][b][j] -> fully
// coalesced reads along j; out [b][a][j] coalesced writes.
__global__ void k_dblur(const float* __restrict__ S, const float* __restrict__ scale,
                        float* __restrict__ out) {
  int j = threadIdx.x;
  int a = blockIdx.x;
  int b = blockIdx.y;
  if (j >= NDET) return;
  float th = (float)a * (float)(3.14159265358979323846 / 299.0);
  float c = cosf(th), s = sinf(th);
  float u = fabsf(c) + fabsf(s);          // bw = 2u
  float u2 = u * u;
  float e1 = exp2f(-2.0f * u2);
  float e2 = exp2f(-8.0f * u2);
  float norm = 1.0f / (1.0f + 2.0f * (e1 + e2));
  float w2c = norm, w1c = e1 * norm, w0c = e2 * norm;
  const float* row = S + (a * NB + b) * NDET;
  float acc = 0.f;
#pragma unroll
  for (int tt = -2; tt <= 2; ++tt) {
    int jr = j + tt;
    if (jr < 0) jr = -jr;
    if (jr > 299) jr = 598 - jr;
    float w = (tt == 0) ? w2c : ((tt == 1 || tt == -1) ? w1c : w0c);
    acc = fmaf(w, row[jr], acc);
  }
  out[(b * NANG + a) * NDET + j] = acc * scale[b];
}

extern "C" void kernel_launch(void* const* d_in, const int* in_sizes, int n_in,
                              void* d_out, int out_size, void* d_ws, size_t ws_size,
                              hipStream_t stream) {
  const float* img   = (const float*)d_in[0];
  const float* att   = (const float*)d_in[1];
  const float* scale = (const float*)d_in[2];
  float* out = (float*)d_out;
  float* ws  = (float*)d_ws;

  // ws layout (floats): Q 148*148*16 uint4 (5.61 MB) | S 300*300*16 (5.76 MB)
  uint4*  Q  = (uint4*)ws;
  float*  S  = ws + 1401856;

  k_prep <<<dim3(10, 10, NB), 256, 0, stream>>>(img, att, Q);
  k_radon<<<dim3(19, NANG),   256, 0, stream>>>(Q, S);
  k_dblur<<<dim3(NANG, NB),   320, 0, stream>>>(S, scale, out);
}